// Round 1
// baseline (200.032 us; speedup 1.0000x reference)
//
#include <hip/hip_runtime.h>

#define BQ   16
#define QLEN 128
#define KLEN 512
#define HD   256
#define VD   256

static __device__ __forceinline__ float fexp2(float x) {
#if __has_builtin(__builtin_amdgcn_exp2f)
    return __builtin_amdgcn_exp2f(x);
#else
    return exp2f(x);
#endif
}
static __device__ __forceinline__ float frcp(float x) {
#if __has_builtin(__builtin_amdgcn_rcpf)
    return __builtin_amdgcn_rcpf(x);
#else
    return 1.0f / x;
#endif
}

// C[M][256] = scale * (A[M][256] x W[256][256]^T); C[r][h] = scale*sum_d A[r][d]*W[h][d]
// grid: (N/64, M/64), block 256. 64x64 tile, 4x4 per thread, BK=16.
__global__ __launch_bounds__(256) void proj_gemm(
    const float* __restrict__ A, const float* __restrict__ W,
    float* __restrict__ C, float scale)
{
    __shared__ float a_s[16][68];   // [dd][row], padded
    __shared__ float w_s[16][68];
    const int t  = threadIdx.x;
    const int tx = t & 15, ty = t >> 4;
    const int bx = blockIdx.x, by = blockIdx.y;
    const int lrow = t >> 2, ld0 = (t & 3) * 4;
    const float* Ab = A + (by * 64 + lrow) * 256;
    const float* Wb = W + (bx * 64 + lrow) * 256;
    float acc[4][4] = {};
    for (int kc = 0; kc < 256; kc += 16) {
        float4 av = *(const float4*)(Ab + kc + ld0);
        float4 wv = *(const float4*)(Wb + kc + ld0);
        __syncthreads();
        a_s[ld0 + 0][lrow] = av.x; a_s[ld0 + 1][lrow] = av.y;
        a_s[ld0 + 2][lrow] = av.z; a_s[ld0 + 3][lrow] = av.w;
        w_s[ld0 + 0][lrow] = wv.x; w_s[ld0 + 1][lrow] = wv.y;
        w_s[ld0 + 2][lrow] = wv.z; w_s[ld0 + 3][lrow] = wv.w;
        __syncthreads();
        #pragma unroll
        for (int dd = 0; dd < 16; ++dd) {
            float4 a4 = *(const float4*)&a_s[dd][ty * 4];
            float4 w4 = *(const float4*)&w_s[dd][tx * 4];
            const float* af = (const float*)&a4;
            const float* wf = (const float*)&w4;
            #pragma unroll
            for (int i = 0; i < 4; ++i)
                #pragma unroll
                for (int j = 0; j < 4; ++j)
                    acc[i][j] += af[i] * wf[j];
        }
    }
    float* Cb = C + (by * 64 + ty * 4) * 256 + bx * 64 + tx * 4;
    #pragma unroll
    for (int i = 0; i < 4; ++i) {
        float4 st;
        st.x = acc[i][0] * scale; st.y = acc[i][1] * scale;
        st.z = acc[i][2] * scale; st.w = acc[i][3] * scale;
        *(float4*)(Cb + i * 256) = st;
    }
}

// Fused scores + masked softmax + PV.
// grid: 512 = 16 b * 32 q-tiles (4 queries each), block 256.
// qp/kp are pre-scaled by 2*log2(e) so tanh(x) = 1 - 2/(exp2(x')+1).
__global__ __launch_bounds__(256) void fused_attn(
    const float* __restrict__ qp, const float* __restrict__ kp,
    const float* __restrict__ values, const float* __restrict__ Wv,
    const int* __restrict__ vlen, float* __restrict__ out)
{
    __shared__ float qp_s[4][HD];
    __shared__ float wv_s[HD];
    __shared__ float sc[4][KLEN];
    __shared__ float wred[4];

    const int t   = threadIdx.x;
    const int blk = blockIdx.x;
    const int b   = blk >> 5;
    const int q0  = (blk & 31) * 4;

    const float w_own = Wv[t];
    wv_s[t] = w_own;
    #pragma unroll
    for (int r = 0; r < 4; ++r)
        qp_s[r][t] = qp[(b * QLEN + q0 + r) * HD + t];

    // wv_sum = sum_h Wv[h] (needed for the tanh identity), computed redundantly
    float ws = w_own;
    #pragma unroll
    for (int off = 32; off > 0; off >>= 1) ws += __shfl_xor(ws, off, 64);
    if ((t & 63) == 0) wred[t >> 6] = ws;
    __syncthreads();
    const float wv_sum = wred[0] + wred[1] + wred[2] + wred[3];

    // ---- Phase 1: scores. Thread t owns k rows {t, t+256} for all 4 queries.
    float acc[4][2] = {};
    const float* kr0 = kp + (b * KLEN + t) * HD;
    const float* kr1 = kr0 + 256 * HD;
    float4 k0 = *(const float4*)(kr0);
    float4 k1 = *(const float4*)(kr1);
    for (int h = 0; h < HD; h += 4) {
        float4 c0 = k0, c1 = k1;
        if (h + 4 < HD) {
            k0 = *(const float4*)(kr0 + h + 4);
            k1 = *(const float4*)(kr1 + h + 4);
        }
        float4 w4 = *(const float4*)&wv_s[h];
        #pragma unroll
        for (int i = 0; i < 4; ++i) {
            float4 q4 = *(const float4*)&qp_s[i][h];
            acc[i][0] += w4.x * frcp(fexp2(q4.x + c0.x) + 1.f)
                       + w4.y * frcp(fexp2(q4.y + c0.y) + 1.f)
                       + w4.z * frcp(fexp2(q4.z + c0.z) + 1.f)
                       + w4.w * frcp(fexp2(q4.w + c0.w) + 1.f);
            acc[i][1] += w4.x * frcp(fexp2(q4.x + c1.x) + 1.f)
                       + w4.y * frcp(fexp2(q4.y + c1.y) + 1.f)
                       + w4.z * frcp(fexp2(q4.z + c1.z) + 1.f)
                       + w4.w * frcp(fexp2(q4.w + c1.w) + 1.f);
        }
    }
    #pragma unroll
    for (int i = 0; i < 4; ++i) {
        sc[i][t]       = wv_sum - 2.f * acc[i][0];
        sc[i][t + 256] = wv_sum - 2.f * acc[i][1];
    }
    __syncthreads();

    // ---- Phase 2: masked softmax. Wave w handles query row w.
    const int lane = t & 63;
    const int row  = t >> 6;
    const int len  = vlen[b];
    float s[8];
    float m = -3.0e38f;
    #pragma unroll
    for (int j = 0; j < 8; ++j) {
        int k = lane + j * 64;
        float v = sc[row][k];
        v = (k < len) ? v : -1.0e6f;
        s[j] = v;
        m = fmaxf(m, v);
    }
    #pragma unroll
    for (int off = 32; off > 0; off >>= 1) m = fmaxf(m, __shfl_xor(m, off, 64));
    float sum = 0.f;
    #pragma unroll
    for (int j = 0; j < 8; ++j) {
        float e = fexp2(1.4426950408889634f * (s[j] - m));  // masked -> exactly 0
        s[j] = e;
        sum += e;
    }
    #pragma unroll
    for (int off = 32; off > 0; off >>= 1) sum += __shfl_xor(sum, off, 64);
    const float rs = frcp(sum);
    #pragma unroll
    for (int j = 0; j < 8; ++j) sc[row][lane + j * 64] = s[j] * rs;
    __syncthreads();

    // ---- Phase 3: PV. Thread t owns output column v = t for all 4 queries.
    float o[4] = {};
    const float* vb = values + (size_t)b * KLEN * VD + t;
    for (int k = 0; k < KLEN; k += 4) {
        float v0 = vb[(k + 0) * VD];
        float v1 = vb[(k + 1) * VD];
        float v2 = vb[(k + 2) * VD];
        float v3 = vb[(k + 3) * VD];
        #pragma unroll
        for (int i = 0; i < 4; ++i) {
            float4 p = *(const float4*)&sc[i][k];
            o[i] += p.x * v0 + p.y * v1 + p.z * v2 + p.w * v3;
        }
    }
    #pragma unroll
    for (int i = 0; i < 4; ++i)
        out[(b * QLEN + q0 + i) * VD + t] = o[i];
}

extern "C" void kernel_launch(void* const* d_in, const int* in_sizes, int n_in,
                              void* d_out, int out_size, void* d_ws, size_t ws_size,
                              hipStream_t stream) {
    const float* queries = (const float*)d_in[0];
    const float* keys    = (const float*)d_in[1];
    const float* values  = (const float*)d_in[2];
    const float* Wq      = (const float*)d_in[3];
    const float* Wk      = (const float*)d_in[4];
    const float* Wv      = (const float*)d_in[5];
    const int*   vl      = (const int*)d_in[6];
    float* out = (float*)d_out;

    float* qp = (float*)d_ws;                 // [2048][256]
    float* kp = qp + 2048 * 256;              // [8192][256]

    const float scale = 2.8853900817779268f;  // 2*log2(e)
    proj_gemm<<<dim3(4, 32),  256, 0, stream>>>(queries, Wq, qp, scale);
    proj_gemm<<<dim3(4, 128), 256, 0, stream>>>(keys,    Wk, kp, scale);
    fused_attn<<<dim3(512),   256, 0, stream>>>(qp, kp, values, Wv, vl, out);
}

// Round 2
// 160.977 us; speedup vs baseline: 1.2426x; 1.2426x over previous
//
#include <hip/hip_runtime.h>

#define BQ   16
#define QLEN 128
#define KLEN 512
#define HD   256
#define VD   256

static __device__ __forceinline__ float fexp2(float x) {
#if __has_builtin(__builtin_amdgcn_exp2f)
    return __builtin_amdgcn_exp2f(x);
#else
    return exp2f(x);
#endif
}
static __device__ __forceinline__ float frcp(float x) {
#if __has_builtin(__builtin_amdgcn_rcpf)
    return __builtin_amdgcn_rcpf(x);
#else
    return 1.0f / x;
#endif
}

// Merged q+k projection GEMM, epilogue stores E = exp2(scale*acc).
// grid (4, 160): by<32 -> queries (2048 rows), else keys (8192 rows).
// 64x64 tile, 4x4/thread, BK=16, register prefetch.
__global__ __launch_bounds__(256) void proj_exp_gemm(
    const float* __restrict__ Qin, const float* __restrict__ Kin,
    const float* __restrict__ Wq, const float* __restrict__ Wk,
    float* __restrict__ Eq, float* __restrict__ Ek)
{
    __shared__ float a_s[16][68];
    __shared__ float w_s[16][68];
    const int t  = threadIdx.x;
    const int tx = t & 15, ty = t >> 4;
    const int bx = blockIdx.x, by = blockIdx.y;
    const bool isq = by < 32;
    const int row0 = isq ? by * 64 : (by - 32) * 64;
    const float* A = isq ? Qin : Kin;
    const float* W = isq ? Wq : Wk;
    float*       C = isq ? Eq : Ek;
    const int lrow = t >> 2, ld0 = (t & 3) * 4;
    const float* Ab = A + (row0 + lrow) * HD;
    const float* Wb = W + (bx * 64 + lrow) * HD;
    float4 av = *(const float4*)(Ab + ld0);
    float4 wv = *(const float4*)(Wb + ld0);
    float acc[4][4] = {};
    for (int kc = 0; kc < HD; kc += 16) {
        __syncthreads();
        a_s[ld0 + 0][lrow] = av.x; a_s[ld0 + 1][lrow] = av.y;
        a_s[ld0 + 2][lrow] = av.z; a_s[ld0 + 3][lrow] = av.w;
        w_s[ld0 + 0][lrow] = wv.x; w_s[ld0 + 1][lrow] = wv.y;
        w_s[ld0 + 2][lrow] = wv.z; w_s[ld0 + 3][lrow] = wv.w;
        __syncthreads();
        if (kc + 16 < HD) {
            av = *(const float4*)(Ab + kc + 16 + ld0);
            wv = *(const float4*)(Wb + kc + 16 + ld0);
        }
        #pragma unroll
        for (int dd = 0; dd < 16; ++dd) {
            float4 a4 = *(const float4*)&a_s[dd][ty * 4];
            float4 w4 = *(const float4*)&w_s[dd][tx * 4];
            const float* af = (const float*)&a4;
            const float* wf = (const float*)&w4;
            #pragma unroll
            for (int i = 0; i < 4; ++i)
                #pragma unroll
                for (int j = 0; j < 4; ++j)
                    acc[i][j] = fmaf(af[i], wf[j], acc[i][j]);
        }
    }
    const float scale = 2.8853900817779268f;  // 2*log2(e)
    float* Cb = C + (row0 + ty * 4) * HD + bx * 64 + tx * 4;
    #pragma unroll
    for (int i = 0; i < 4; ++i) {
        float4 st;
        st.x = fexp2(acc[i][0] * scale); st.y = fexp2(acc[i][1] * scale);
        st.z = fexp2(acc[i][2] * scale); st.w = fexp2(acc[i][3] * scale);
        *(float4*)(Cb + i * HD) = st;
    }
}

// Fused scores + masked softmax + PV. grid 512 = 16 b * 32 q-tiles(4).
// block 512 threads (8 waves). tanh(q+k) = 1 - 2/(Eq*Ek+1).
__global__ __launch_bounds__(512, 4) void fused_attn(
    const float* __restrict__ Eq, const float* __restrict__ Ek,
    const float* __restrict__ values, const float* __restrict__ Wv,
    const int* __restrict__ vlen, float* __restrict__ out)
{
    __shared__ float eq_s[4][HD];
    __shared__ float wv_s[HD];
    __shared__ float sc[4][KLEN];
    __shared__ float po[8][4][VD];
    __shared__ float wred[4];

    const int t    = threadIdx.x;
    const int b    = blockIdx.x >> 5;
    const int q0   = (blockIdx.x & 31) * 4;
    const int lane = t & 63;
    const int wid  = t >> 6;

    {   // stage Eq rows + Wv
        const int h = t & 255, rr = t >> 8;
        eq_s[rr][h]     = Eq[(b * QLEN + q0 + rr) * HD + h];
        eq_s[rr + 2][h] = Eq[(b * QLEN + q0 + rr + 2) * HD + h];
        if (t < HD) {
            wv_s[t] = Wv[t];
            float ws = wv_s[t];
            #pragma unroll
            for (int off = 32; off > 0; off >>= 1) ws += __shfl_xor(ws, off, 64);
            if (lane == 0) wred[wid] = ws;
        }
    }
    __syncthreads();
    const float wv_sum = wred[0] + wred[1] + wred[2] + wred[3];

    // ---- Phase 1: scores. Thread t owns k-row t for 4 queries.
    const float* kr = Ek + (size_t)(b * KLEN + t) * HD;
    float4 ek = *(const float4*)kr;
    float acc[4] = {};
    for (int h = 0; h < HD; h += 4) {
        float4 e = ek;
        if (h + 4 < HD) ek = *(const float4*)(kr + h + 4);
        float4 w4 = *(const float4*)&wv_s[h];
        #pragma unroll
        for (int i = 0; i < 4; ++i) {
            float4 q4 = *(const float4*)&eq_s[i][h];
            float d0 = fmaf(q4.x, e.x, 1.f);
            float d1 = fmaf(q4.y, e.y, 1.f);
            float d2 = fmaf(q4.z, e.z, 1.f);
            float d3 = fmaf(q4.w, e.w, 1.f);
            // w0/d0 + w1/d1 = (w0*d1 + w1*d0) * rcp(d0*d1)
            float n01 = fmaf(w4.y, d0, w4.x * d1);
            float n23 = fmaf(w4.w, d2, w4.z * d3);
            float r01 = frcp(d0 * d1);
            float r23 = frcp(d2 * d3);
            acc[i] = fmaf(n01, r01, acc[i]);
            acc[i] = fmaf(n23, r23, acc[i]);
        }
    }
    #pragma unroll
    for (int i = 0; i < 4; ++i) sc[i][t] = fmaf(-2.f, acc[i], wv_sum);
    __syncthreads();

    // ---- Phase 2: masked softmax, wave w (w<4) handles row w.
    if (wid < 4) {
        const int len = vlen[b];
        float s[8];
        float m = -3.0e38f;
        #pragma unroll
        for (int j = 0; j < 8; ++j) {
            int k = lane + j * 64;
            float v = sc[wid][k];
            v = (k < len) ? v : -1.0e6f;
            s[j] = v;
            m = fmaxf(m, v);
        }
        #pragma unroll
        for (int off = 32; off > 0; off >>= 1) m = fmaxf(m, __shfl_xor(m, off, 64));
        float sum = 0.f;
        #pragma unroll
        for (int j = 0; j < 8; ++j) {
            float e = fexp2(1.4426950408889634f * (s[j] - m));
            s[j] = e;
            sum += e;
        }
        #pragma unroll
        for (int off = 32; off > 0; off >>= 1) sum += __shfl_xor(sum, off, 64);
        const float rs = frcp(sum);
        #pragma unroll
        for (int j = 0; j < 8; ++j) sc[wid][lane + j * 64] = s[j] * rs;
    }
    __syncthreads();

    // ---- Phase 3: PV, k-sliced. Wave wid owns k in [wid*64, wid*64+64),
    // lane covers 4 v-cols -> coalesced float4 v loads.
    const int c4 = lane * 4;
    const float* vb = values + (size_t)b * KLEN * VD + (size_t)(wid * 64) * VD + c4;
    float o[4][4] = {};
    for (int kk = 0; kk < 64; kk += 4) {
        const int k = wid * 64 + kk;
        float4 p[4];
        p[0] = *(const float4*)&sc[0][k];
        p[1] = *(const float4*)&sc[1][k];
        p[2] = *(const float4*)&sc[2][k];
        p[3] = *(const float4*)&sc[3][k];
        #pragma unroll
        for (int j = 0; j < 4; ++j) {
            float4 v4 = *(const float4*)(vb + (size_t)(kk + j) * VD);
            #pragma unroll
            for (int r = 0; r < 4; ++r) {
                float pj = ((const float*)&p[r])[j];
                o[r][0] = fmaf(pj, v4.x, o[r][0]);
                o[r][1] = fmaf(pj, v4.y, o[r][1]);
                o[r][2] = fmaf(pj, v4.z, o[r][2]);
                o[r][3] = fmaf(pj, v4.w, o[r][3]);
            }
        }
    }
    #pragma unroll
    for (int r = 0; r < 4; ++r) {
        float4 st; st.x = o[r][0]; st.y = o[r][1]; st.z = o[r][2]; st.w = o[r][3];
        *(float4*)&po[wid][r][c4] = st;
    }
    __syncthreads();

    // reduce 8 k-slices -> output
    #pragma unroll
    for (int u = 0; u < 2; ++u) {
        int idx = t + u * 512;
        int r = idx >> 8, c = idx & 255;
        float s = 0.f;
        #pragma unroll
        for (int sl = 0; sl < 8; ++sl) s += po[sl][r][c];
        out[(b * QLEN + q0 + r) * VD + c] = s;
    }
}

extern "C" void kernel_launch(void* const* d_in, const int* in_sizes, int n_in,
                              void* d_out, int out_size, void* d_ws, size_t ws_size,
                              hipStream_t stream) {
    const float* queries = (const float*)d_in[0];
    const float* keys    = (const float*)d_in[1];
    const float* values  = (const float*)d_in[2];
    const float* Wq      = (const float*)d_in[3];
    const float* Wk      = (const float*)d_in[4];
    const float* Wv      = (const float*)d_in[5];
    const int*   vl      = (const int*)d_in[6];
    float* out = (float*)d_out;

    float* Eq = (float*)d_ws;                 // [2048][256]
    float* Ek = Eq + 2048 * 256;              // [8192][256]

    proj_exp_gemm<<<dim3(4, 160), 256, 0, stream>>>(queries, keys, Wq, Wk, Eq, Ek);
    fused_attn<<<dim3(512), 512, 0, stream>>>(Eq, Ek, values, Wv, vl, out);
}

// Round 3
// 155.020 us; speedup vs baseline: 1.2904x; 1.0384x over previous
//
#include <hip/hip_runtime.h>

#define BQ   16
#define QLEN 128
#define KLEN 512
#define HD   256
#define VD   256

static __device__ __forceinline__ float fexp2(float x) {
#if __has_builtin(__builtin_amdgcn_exp2f)
    return __builtin_amdgcn_exp2f(x);
#else
    return exp2f(x);
#endif
}
static __device__ __forceinline__ float frcp(float x) {
#if __has_builtin(__builtin_amdgcn_rcpf)
    return __builtin_amdgcn_rcpf(x);
#else
    return 1.0f / x;
#endif
}

#define EXP_SCALE 2.8853900817779268f   // 2*log2(e)

// Merged q+k projection GEMM. Epilogue stores E = exp2(scale*acc).
// Queries -> Eq row-major [2048][256]. Keys -> Ekt TRANSPOSED [b][h][k]
// (k contiguous) via LDS transpose, so fused phase-1 loads coalesce.
// grid (4, 160): by<32 -> queries, else keys. 64x64 tile, 4x4/thread,
// BK=16, double-buffered LDS (1 barrier/iter), register prefetch.
__global__ __launch_bounds__(256) void proj_exp_gemm(
    const float* __restrict__ Qin, const float* __restrict__ Kin,
    const float* __restrict__ Wq, const float* __restrict__ Wk,
    float* __restrict__ Eq, float* __restrict__ Ekt)
{
    __shared__ union {
        struct { float a[2][16][68]; float w[2][16][68]; } s;
        float tb[64][65];
    } sh;

    const int t  = threadIdx.x;
    const int tx = t & 15, ty = t >> 4;
    const int bx = blockIdx.x, by = blockIdx.y;
    const bool isq = by < 32;
    const int row0 = isq ? by * 64 : (by - 32) * 64;
    const float* A = isq ? Qin : Kin;
    const float* W = isq ? Wq : Wk;
    const int lrow = t >> 2, ld0 = (t & 3) * 4;
    const float* Ab = A + (row0 + lrow) * HD;
    const float* Wb = W + (bx * 64 + lrow) * HD;

    float4 av = *(const float4*)(Ab + ld0);
    float4 wv = *(const float4*)(Wb + ld0);
    // stage tile 0 into buffer 0
    sh.s.a[0][ld0 + 0][lrow] = av.x; sh.s.a[0][ld0 + 1][lrow] = av.y;
    sh.s.a[0][ld0 + 2][lrow] = av.z; sh.s.a[0][ld0 + 3][lrow] = av.w;
    sh.s.w[0][ld0 + 0][lrow] = wv.x; sh.s.w[0][ld0 + 1][lrow] = wv.y;
    sh.s.w[0][ld0 + 2][lrow] = wv.z; sh.s.w[0][ld0 + 3][lrow] = wv.w;

    float acc[4][4] = {};
    int p = 0;
    for (int kc = 0; kc < HD; kc += 16) {
        if (kc + 16 < HD) {
            av = *(const float4*)(Ab + kc + 16 + ld0);
            wv = *(const float4*)(Wb + kc + 16 + ld0);
        }
        __syncthreads();
        if (kc + 16 < HD) {
            const int np = p ^ 1;
            sh.s.a[np][ld0 + 0][lrow] = av.x; sh.s.a[np][ld0 + 1][lrow] = av.y;
            sh.s.a[np][ld0 + 2][lrow] = av.z; sh.s.a[np][ld0 + 3][lrow] = av.w;
            sh.s.w[np][ld0 + 0][lrow] = wv.x; sh.s.w[np][ld0 + 1][lrow] = wv.y;
            sh.s.w[np][ld0 + 2][lrow] = wv.z; sh.s.w[np][ld0 + 3][lrow] = wv.w;
        }
        #pragma unroll
        for (int dd = 0; dd < 16; ++dd) {
            float4 a4 = *(const float4*)&sh.s.a[p][dd][ty * 4];
            float4 w4 = *(const float4*)&sh.s.w[p][dd][tx * 4];
            const float* af = (const float*)&a4;
            const float* wf = (const float*)&w4;
            #pragma unroll
            for (int i = 0; i < 4; ++i)
                #pragma unroll
                for (int j = 0; j < 4; ++j)
                    acc[i][j] = fmaf(af[i], wf[j], acc[i][j]);
        }
        p ^= 1;
    }

    float e[4][4];
    #pragma unroll
    for (int i = 0; i < 4; ++i)
        #pragma unroll
        for (int j = 0; j < 4; ++j)
            e[i][j] = fexp2(acc[i][j] * EXP_SCALE);

    if (isq) {
        float* Cb = Eq + (row0 + ty * 4) * HD + bx * 64 + tx * 4;
        #pragma unroll
        for (int i = 0; i < 4; ++i) {
            float4 st; st.x = e[i][0]; st.y = e[i][1]; st.z = e[i][2]; st.w = e[i][3];
            *(float4*)(Cb + i * HD) = st;
        }
    } else {
        __syncthreads();   // done reading gemm buffers; reuse as transpose buf
        #pragma unroll
        for (int j = 0; j < 4; ++j) {
            float4 st; st.x = e[0][j]; st.y = e[1][j]; st.z = e[2][j]; st.w = e[3][j];
            *(float4*)&sh.tb[tx * 4 + j][ty * 4] = st;
        }
        __syncthreads();
        const int r = t >> 2, c0 = (t & 3) * 16;
        const int b = row0 >> 9, kbase = row0 & 511;
        float* dst = Ekt + ((size_t)b * HD + bx * 64 + r) * KLEN + kbase + c0;
        #pragma unroll
        for (int u = 0; u < 4; ++u) {
            float4 v = *(const float4*)&sh.tb[r][c0 + u * 4];
            *(float4*)(dst + u * 4) = v;
        }
    }
}

// Fused scores + masked softmax + PV. grid 512 = 16 b * 32 q-tiles(4).
// block 512 (8 waves). Wave wid: h-slice hs=wid&3 (64 h), k-quarter
// khalf=wid>>2 (256 k). Lane owns 4 consecutive k -> coalesced Ekt loads.
// tanh identity: sum_j w_j*tanh(x_j) = sum w - 2*sum w_j/(Eq*Ek+1),
// 4 h-terms share one rcp.
__global__ __launch_bounds__(512, 4) void fused_attn(
    const float* __restrict__ Eq, const float* __restrict__ Ekt,
    const float* __restrict__ values, const float* __restrict__ Wv,
    const int* __restrict__ vlen, float* __restrict__ out)
{
    __shared__ float eq_s[4][HD];
    __shared__ float wv_s[HD];
    __shared__ float sc[4][KLEN];
    __shared__ float ps[4][4][KLEN];   // phase-1 partials; reused as po[8][4][VD]
    __shared__ float wred[4];

    const int t    = threadIdx.x;
    const int b    = blockIdx.x >> 5;
    const int q0   = (blockIdx.x & 31) * 4;
    const int lane = t & 63;
    const int wid  = t >> 6;

    {   // stage Eq rows + Wv
        const int h = t & 255, rr = t >> 8;
        eq_s[rr][h]     = Eq[(b * QLEN + q0 + rr) * HD + h];
        eq_s[rr + 2][h] = Eq[(b * QLEN + q0 + rr + 2) * HD + h];
        if (t < HD) {
            float w = Wv[t];
            wv_s[t] = w;
            float ws = w;
            #pragma unroll
            for (int off = 32; off > 0; off >>= 1) ws += __shfl_xor(ws, off, 64);
            if (lane == 0) wred[wid] = ws;
        }
    }
    __syncthreads();
    const float wv_sum = wred[0] + wred[1] + wred[2] + wred[3];

    // ---- Phase 1: scores, coalesced.
    const int hs    = wid & 3, khalf = wid >> 2;
    const int hbase = hs * 64;
    const int k4    = khalf * 256 + lane * 4;
    const float* ek = Ekt + ((size_t)b * HD + hbase) * KLEN + k4;
    float acc[4][4] = {};   // [q][kj]
    for (int hh = 0; hh < 64; hh += 4) {
        float4 e0 = *(const float4*)(ek + (size_t)(hh + 0) * KLEN);
        float4 e1 = *(const float4*)(ek + (size_t)(hh + 1) * KLEN);
        float4 e2 = *(const float4*)(ek + (size_t)(hh + 2) * KLEN);
        float4 e3 = *(const float4*)(ek + (size_t)(hh + 3) * KLEN);
        const float* E0 = (const float*)&e0;
        const float* E1 = (const float*)&e1;
        const float* E2 = (const float*)&e2;
        const float* E3 = (const float*)&e3;
        const float w0 = wv_s[hbase + hh + 0], w1 = wv_s[hbase + hh + 1];
        const float w2 = wv_s[hbase + hh + 2], w3 = wv_s[hbase + hh + 3];
        #pragma unroll
        for (int i = 0; i < 4; ++i) {
            const float a0 = eq_s[i][hbase + hh + 0], a1 = eq_s[i][hbase + hh + 1];
            const float a2 = eq_s[i][hbase + hh + 2], a3 = eq_s[i][hbase + hh + 3];
            #pragma unroll
            for (int j = 0; j < 4; ++j) {
                float d0 = fmaf(a0, E0[j], 1.f);
                float d1 = fmaf(a1, E1[j], 1.f);
                float d2 = fmaf(a2, E2[j], 1.f);
                float d3 = fmaf(a3, E3[j], 1.f);
                float d01 = d0 * d1, d23 = d2 * d3;
                float n01 = fmaf(w1, d0, w0 * d1);
                float n23 = fmaf(w3, d2, w2 * d3);
                float top = fmaf(n23, d01, n01 * d23);
                acc[i][j] = fmaf(top, frcp(d01 * d23), acc[i][j]);
            }
        }
    }
    #pragma unroll
    for (int i = 0; i < 4; ++i) {
        float4 st; st.x = acc[i][0]; st.y = acc[i][1]; st.z = acc[i][2]; st.w = acc[i][3];
        *(float4*)&ps[hs][i][k4] = st;
    }
    __syncthreads();

    {   // reduce 4 h-slices, finalize scores
        const int q = t >> 7, kk = (t & 127) * 4;
        float4 s0 = *(const float4*)&ps[0][q][kk];
        float4 s1 = *(const float4*)&ps[1][q][kk];
        float4 s2 = *(const float4*)&ps[2][q][kk];
        float4 s3 = *(const float4*)&ps[3][q][kk];
        float4 r;
        r.x = fmaf(-2.f, s0.x + s1.x + s2.x + s3.x, wv_sum);
        r.y = fmaf(-2.f, s0.y + s1.y + s2.y + s3.y, wv_sum);
        r.z = fmaf(-2.f, s0.z + s1.z + s2.z + s3.z, wv_sum);
        r.w = fmaf(-2.f, s0.w + s1.w + s2.w + s3.w, wv_sum);
        *(float4*)&sc[q][kk] = r;
    }
    __syncthreads();

    // ---- Phase 2: masked softmax, wave w (w<4) handles row w.
    if (wid < 4) {
        const int len = vlen[b];
        float s[8];
        float m = -3.0e38f;
        #pragma unroll
        for (int j = 0; j < 8; ++j) {
            int k = lane + j * 64;
            float v = sc[wid][k];
            v = (k < len) ? v : -1.0e6f;
            s[j] = v;
            m = fmaxf(m, v);
        }
        #pragma unroll
        for (int off = 32; off > 0; off >>= 1) m = fmaxf(m, __shfl_xor(m, off, 64));
        float sum = 0.f;
        #pragma unroll
        for (int j = 0; j < 8; ++j) {
            float ev = fexp2(1.4426950408889634f * (s[j] - m));
            s[j] = ev;
            sum += ev;
        }
        #pragma unroll
        for (int off = 32; off > 0; off >>= 1) sum += __shfl_xor(sum, off, 64);
        const float rs = frcp(sum);
        #pragma unroll
        for (int j = 0; j < 8; ++j) sc[wid][lane + j * 64] = s[j] * rs;
    }
    __syncthreads();

    // ---- Phase 3: PV, k-sliced. Wave wid owns k in [wid*64, +64),
    // lane covers 4 v-cols -> coalesced float4 v loads. po aliases ps.
    float (*po)[4][VD] = (float (*)[4][VD])ps;
    const int c4 = lane * 4;
    const float* vb = values + (size_t)b * KLEN * VD + (size_t)(wid * 64) * VD + c4;
    float o[4][4] = {};
    for (int kk = 0; kk < 64; kk += 4) {
        const int k = wid * 64 + kk;
        float4 pr[4];
        pr[0] = *(const float4*)&sc[0][k];
        pr[1] = *(const float4*)&sc[1][k];
        pr[2] = *(const float4*)&sc[2][k];
        pr[3] = *(const float4*)&sc[3][k];
        #pragma unroll
        for (int j = 0; j < 4; ++j) {
            float4 v4 = *(const float4*)(vb + (size_t)(kk + j) * VD);
            #pragma unroll
            for (int r = 0; r < 4; ++r) {
                float pj = ((const float*)&pr[r])[j];
                o[r][0] = fmaf(pj, v4.x, o[r][0]);
                o[r][1] = fmaf(pj, v4.y, o[r][1]);
                o[r][2] = fmaf(pj, v4.z, o[r][2]);
                o[r][3] = fmaf(pj, v4.w, o[r][3]);
            }
        }
    }
    #pragma unroll
    for (int r = 0; r < 4; ++r) {
        float4 st; st.x = o[r][0]; st.y = o[r][1]; st.z = o[r][2]; st.w = o[r][3];
        *(float4*)&po[wid][r][c4] = st;
    }
    __syncthreads();

    #pragma unroll
    for (int u = 0; u < 2; ++u) {
        int idx = t + u * 512;
        int r = idx >> 8, c = idx & 255;
        float s = 0.f;
        #pragma unroll
        for (int sl = 0; sl < 8; ++sl) s += po[sl][r][c];
        out[(b * QLEN + q0 + r) * VD + c] = s;
    }
}

extern "C" void kernel_launch(void* const* d_in, const int* in_sizes, int n_in,
                              void* d_out, int out_size, void* d_ws, size_t ws_size,
                              hipStream_t stream) {
    const float* queries = (const float*)d_in[0];
    const float* keys    = (const float*)d_in[1];
    const float* values  = (const float*)d_in[2];
    const float* Wq      = (const float*)d_in[3];
    const float* Wk      = (const float*)d_in[4];
    const float* Wv      = (const float*)d_in[5];
    const int*   vl      = (const int*)d_in[6];
    float* out = (float*)d_out;

    float* Eq  = (float*)d_ws;                // [2048][256] row-major
    float* Ekt = Eq + 2048 * 256;             // [16][256][512] transposed

    proj_exp_gemm<<<dim3(4, 160), 256, 0, stream>>>(queries, keys, Wq, Wk, Eq, Ekt);
    fused_attn<<<dim3(512), 512, 0, stream>>>(Eq, Ekt, values, Wv, vl, out);
}

// Round 4
// 123.913 us; speedup vs baseline: 1.6143x; 1.2510x over previous
//
#include <hip/hip_runtime.h>

#define BQ   16
#define QLEN 128
#define KLEN 512
#define HD   256
#define VD   256

typedef __bf16 bf16x8 __attribute__((ext_vector_type(8)));
typedef __bf16 bf16x4 __attribute__((ext_vector_type(4)));
typedef float  f32x4  __attribute__((ext_vector_type(4)));

static __device__ __forceinline__ float fexp2(float x) {
#if __has_builtin(__builtin_amdgcn_exp2f)
    return __builtin_amdgcn_exp2f(x);
#else
    return exp2f(x);
#endif
}
static __device__ __forceinline__ float frcp(float x) {
#if __has_builtin(__builtin_amdgcn_rcpf)
    return __builtin_amdgcn_rcpf(x);
#else
    return 1.0f / x;
#endif
}

#define EXP_SCALE 2.8853900817779268f   // 2*log2(e)

// ---------------- W split kernel: fp32 -> bf16 hi + lo ----------------
// 131072 elems (Wq then Wk). grid 128 x 256, 4 elems/thread.
__global__ __launch_bounds__(256) void conv_w(
    const float* __restrict__ Wq, const float* __restrict__ Wk,
    __bf16* __restrict__ hi, __bf16* __restrict__ lo)
{
    const int t = blockIdx.x * 256 + threadIdx.x;
    const int e = t * 4;
    const float* src = (e < 65536) ? (Wq + e) : (Wk + (e - 65536));
    float4 v = *(const float4*)src;
    float f[4] = {v.x, v.y, v.z, v.w};
    bf16x4 h, l;
    #pragma unroll
    for (int j = 0; j < 4; ++j) {
        __bf16 hv = (__bf16)f[j];
        h[j] = hv;
        l[j] = (__bf16)(f[j] - (float)hv);
    }
    *(bf16x4*)(hi + e) = h;
    *(bf16x4*)(lo + e) = l;
}

// ---------------- MFMA projection GEMM (split-bf16, ~fp32 accurate) ----
// C[r][h] = sum_d A[r][d]*W[h][d];  E = exp2(EXP_SCALE * C).
// A rows: 0..2047 queries, 2048..10239 keys (selected via by).
// grid (2, 160): by<32 -> queries -> Eq row-major; else keys -> Ekt
// transposed [b][h][k] (free transpose: acc regs are 4 consecutive rows
// = 4 consecutive k -> one float4 store).
// Tile 64x128, BK=32, 4 waves (wave w owns cols w*32..w*32+31).
// Split trick: a = hi+lo (bf16), a*w ~= hi*Whi + hi*Wlo + lo*Whi.
__global__ __launch_bounds__(256) void mfma_proj(
    const float* __restrict__ queries, const float* __restrict__ keys,
    const __bf16* __restrict__ Whi_g, const __bf16* __restrict__ Wlo_g,
    float* __restrict__ Eq, float* __restrict__ Ekt)
{
    __shared__ __bf16 Ahi_s[64][40];    // stride 40 bf16 = 80 B: 2-way max
    __shared__ __bf16 Alo_s[64][40];
    __shared__ __bf16 Whi_s[128][40];
    __shared__ __bf16 Wlo_s[128][40];

    const int t    = threadIdx.x;
    const int ln   = t & 63;
    const int w    = t >> 6;
    const int p    = ln & 15;
    const int quad = ln >> 4;
    const int bx = blockIdx.x, by = blockIdx.y;
    const bool isq = by < 32;
    const int row0 = by * 64;
    const int col0 = bx * 128;

    const float* Ag = isq ? (queries + (size_t)row0 * HD)
                          : (keys + (size_t)(row0 - 2048) * HD);
    const __bf16* Wh = Whi_g + (isq ? 0 : 65536);
    const __bf16* Wl = Wlo_g + (isq ? 0 : 65536);

    const int ar = t >> 2, ac = (t & 3) * 8;     // A stage: 8 floats/thread
    const int wr = t >> 1, wc = (t & 1) * 16;    // W stage: 16 bf16/thread/buf

    float4 pa0, pa1;
    uint4 ph0, ph1, pl0, pl1;
    {
        const float* ap = Ag + ar * HD + ac;
        pa0 = *(const float4*)ap;
        pa1 = *(const float4*)(ap + 4);
        const size_t wb = (size_t)(col0 + wr) * HD + wc;
        ph0 = *(const uint4*)(Wh + wb);
        ph1 = *(const uint4*)(Wh + wb + 8);
        pl0 = *(const uint4*)(Wl + wb);
        pl1 = *(const uint4*)(Wl + wb + 8);
    }

    f32x4 acc[4][2] = {};

    for (int s = 0; s < 8; ++s) {
        __syncthreads();
        {
            float f[8] = {pa0.x, pa0.y, pa0.z, pa0.w, pa1.x, pa1.y, pa1.z, pa1.w};
            bf16x8 h, l;
            #pragma unroll
            for (int j = 0; j < 8; ++j) {
                __bf16 hv = (__bf16)f[j];
                h[j] = hv;
                l[j] = (__bf16)(f[j] - (float)hv);
            }
            *(bf16x8*)&Ahi_s[ar][ac] = h;
            *(bf16x8*)&Alo_s[ar][ac] = l;
            *(uint4*)&Whi_s[wr][wc]     = ph0;
            *(uint4*)&Whi_s[wr][wc + 8] = ph1;
            *(uint4*)&Wlo_s[wr][wc]     = pl0;
            *(uint4*)&Wlo_s[wr][wc + 8] = pl1;
        }
        __syncthreads();
        if (s < 7) {   // prefetch next K-slab while computing this one
            const int kc = (s + 1) * 32;
            const float* ap = Ag + ar * HD + kc + ac;
            pa0 = *(const float4*)ap;
            pa1 = *(const float4*)(ap + 4);
            const size_t wb = (size_t)(col0 + wr) * HD + kc + wc;
            ph0 = *(const uint4*)(Wh + wb);
            ph1 = *(const uint4*)(Wh + wb + 8);
            pl0 = *(const uint4*)(Wl + wb);
            pl1 = *(const uint4*)(Wl + wb + 8);
        }
        bf16x8 ah[4], al[4], bh[2], bl[2];
        #pragma unroll
        for (int mi = 0; mi < 4; ++mi) {
            ah[mi] = *(const bf16x8*)&Ahi_s[mi * 16 + p][quad * 8];
            al[mi] = *(const bf16x8*)&Alo_s[mi * 16 + p][quad * 8];
        }
        #pragma unroll
        for (int ci = 0; ci < 2; ++ci) {
            const int hrow = w * 32 + ci * 16 + p;
            bh[ci] = *(const bf16x8*)&Whi_s[hrow][quad * 8];
            bl[ci] = *(const bf16x8*)&Wlo_s[hrow][quad * 8];
        }
        #pragma unroll
        for (int mi = 0; mi < 4; ++mi)
            #pragma unroll
            for (int ci = 0; ci < 2; ++ci) {
                acc[mi][ci] = __builtin_amdgcn_mfma_f32_16x16x32_bf16(ah[mi], bh[ci], acc[mi][ci], 0, 0, 0);
                acc[mi][ci] = __builtin_amdgcn_mfma_f32_16x16x32_bf16(ah[mi], bl[ci], acc[mi][ci], 0, 0, 0);
                acc[mi][ci] = __builtin_amdgcn_mfma_f32_16x16x32_bf16(al[mi], bh[ci], acc[mi][ci], 0, 0, 0);
            }
    }

    // epilogue: C/D layout col=lane&15, row=quad*4+reg
    #pragma unroll
    for (int mi = 0; mi < 4; ++mi)
        #pragma unroll
        for (int ci = 0; ci < 2; ++ci) {
            const int H  = col0 + w * 32 + ci * 16 + p;
            const int rl = mi * 16 + quad * 4;
            float e0 = fexp2(acc[mi][ci][0] * EXP_SCALE);
            float e1 = fexp2(acc[mi][ci][1] * EXP_SCALE);
            float e2 = fexp2(acc[mi][ci][2] * EXP_SCALE);
            float e3 = fexp2(acc[mi][ci][3] * EXP_SCALE);
            if (isq) {
                float* dst = Eq + (size_t)(row0 + rl) * HD + H;
                dst[0] = e0; dst[HD] = e1; dst[2 * HD] = e2; dst[3 * HD] = e3;
            } else {
                const int kr = row0 - 2048 + rl;
                const int b = kr >> 9, k0 = kr & 511;
                float4 st; st.x = e0; st.y = e1; st.z = e2; st.w = e3;
                *(float4*)(Ekt + ((size_t)b * HD + H) * KLEN + k0) = st;
            }
        }
}

// ---------------- fallback fp32 projection (if ws too small) ----------
__global__ __launch_bounds__(256) void proj_exp_gemm(
    const float* __restrict__ Qin, const float* __restrict__ Kin,
    const float* __restrict__ Wq, const float* __restrict__ Wk,
    float* __restrict__ Eq, float* __restrict__ Ekt)
{
    __shared__ union {
        struct { float a[2][16][68]; float w[2][16][68]; } s;
        float tb[64][65];
    } sh;

    const int t  = threadIdx.x;
    const int tx = t & 15, ty = t >> 4;
    const int bx = blockIdx.x, by = blockIdx.y;
    const bool isq = by < 32;
    const int row0 = isq ? by * 64 : (by - 32) * 64;
    const float* A = isq ? Qin : Kin;
    const float* W = isq ? Wq : Wk;
    const int lrow = t >> 2, ld0 = (t & 3) * 4;
    const float* Ab = A + (row0 + lrow) * HD;
    const float* Wb = W + (bx * 64 + lrow) * HD;

    float4 av = *(const float4*)(Ab + ld0);
    float4 wv = *(const float4*)(Wb + ld0);
    sh.s.a[0][ld0 + 0][lrow] = av.x; sh.s.a[0][ld0 + 1][lrow] = av.y;
    sh.s.a[0][ld0 + 2][lrow] = av.z; sh.s.a[0][ld0 + 3][lrow] = av.w;
    sh.s.w[0][ld0 + 0][lrow] = wv.x; sh.s.w[0][ld0 + 1][lrow] = wv.y;
    sh.s.w[0][ld0 + 2][lrow] = wv.z; sh.s.w[0][ld0 + 3][lrow] = wv.w;

    float acc[4][4] = {};
    int p = 0;
    for (int kc = 0; kc < HD; kc += 16) {
        if (kc + 16 < HD) {
            av = *(const float4*)(Ab + kc + 16 + ld0);
            wv = *(const float4*)(Wb + kc + 16 + ld0);
        }
        __syncthreads();
        if (kc + 16 < HD) {
            const int np = p ^ 1;
            sh.s.a[np][ld0 + 0][lrow] = av.x; sh.s.a[np][ld0 + 1][lrow] = av.y;
            sh.s.a[np][ld0 + 2][lrow] = av.z; sh.s.a[np][ld0 + 3][lrow] = av.w;
            sh.s.w[np][ld0 + 0][lrow] = wv.x; sh.s.w[np][ld0 + 1][lrow] = wv.y;
            sh.s.w[np][ld0 + 2][lrow] = wv.z; sh.s.w[np][ld0 + 3][lrow] = wv.w;
        }
        #pragma unroll
        for (int dd = 0; dd < 16; ++dd) {
            float4 a4 = *(const float4*)&sh.s.a[p][dd][ty * 4];
            float4 w4 = *(const float4*)&sh.s.w[p][dd][tx * 4];
            const float* af = (const float*)&a4;
            const float* wf = (const float*)&w4;
            #pragma unroll
            for (int i = 0; i < 4; ++i)
                #pragma unroll
                for (int j = 0; j < 4; ++j)
                    acc[i][j] = fmaf(af[i], wf[j], acc[i][j]);
        }
        p ^= 1;
    }

    float e[4][4];
    #pragma unroll
    for (int i = 0; i < 4; ++i)
        #pragma unroll
        for (int j = 0; j < 4; ++j)
            e[i][j] = fexp2(acc[i][j] * EXP_SCALE);

    if (isq) {
        float* Cb = Eq + (row0 + ty * 4) * HD + bx * 64 + tx * 4;
        #pragma unroll
        for (int i = 0; i < 4; ++i) {
            float4 st; st.x = e[i][0]; st.y = e[i][1]; st.z = e[i][2]; st.w = e[i][3];
            *(float4*)(Cb + i * HD) = st;
        }
    } else {
        __syncthreads();
        #pragma unroll
        for (int j = 0; j < 4; ++j) {
            float4 st; st.x = e[0][j]; st.y = e[1][j]; st.z = e[2][j]; st.w = e[3][j];
            *(float4*)&sh.tb[tx * 4 + j][ty * 4] = st;
        }
        __syncthreads();
        const int r = t >> 2, c0 = (t & 3) * 16;
        const int b = row0 >> 9, kbase = row0 & 511;
        float* dst = Ekt + ((size_t)b * HD + bx * 64 + r) * KLEN + kbase + c0;
        #pragma unroll
        for (int u = 0; u < 4; ++u) {
            float4 v = *(const float4*)&sh.tb[r][c0 + u * 4];
            *(float4*)(dst + u * 4) = v;
        }
    }
}

// ---------------- fused scores + masked softmax + PV (unchanged) ------
__global__ __launch_bounds__(512, 4) void fused_attn(
    const float* __restrict__ Eq, const float* __restrict__ Ekt,
    const float* __restrict__ values, const float* __restrict__ Wv,
    const int* __restrict__ vlen, float* __restrict__ out)
{
    __shared__ float eq_s[4][HD];
    __shared__ float wv_s[HD];
    __shared__ float sc[4][KLEN];
    __shared__ float ps[4][4][KLEN];
    __shared__ float wred[4];

    const int t    = threadIdx.x;
    const int b    = blockIdx.x >> 5;
    const int q0   = (blockIdx.x & 31) * 4;
    const int lane = t & 63;
    const int wid  = t >> 6;

    {
        const int h = t & 255, rr = t >> 8;
        eq_s[rr][h]     = Eq[(b * QLEN + q0 + rr) * HD + h];
        eq_s[rr + 2][h] = Eq[(b * QLEN + q0 + rr + 2) * HD + h];
        if (t < HD) {
            float w = Wv[t];
            wv_s[t] = w;
            float ws = w;
            #pragma unroll
            for (int off = 32; off > 0; off >>= 1) ws += __shfl_xor(ws, off, 64);
            if (lane == 0) wred[wid] = ws;
        }
    }
    __syncthreads();
    const float wv_sum = wred[0] + wred[1] + wred[2] + wred[3];

    const int hs    = wid & 3, khalf = wid >> 2;
    const int hbase = hs * 64;
    const int k4    = khalf * 256 + lane * 4;
    const float* ek = Ekt + ((size_t)b * HD + hbase) * KLEN + k4;
    float acc[4][4] = {};
    for (int hh = 0; hh < 64; hh += 4) {
        float4 e0 = *(const float4*)(ek + (size_t)(hh + 0) * KLEN);
        float4 e1 = *(const float4*)(ek + (size_t)(hh + 1) * KLEN);
        float4 e2 = *(const float4*)(ek + (size_t)(hh + 2) * KLEN);
        float4 e3 = *(const float4*)(ek + (size_t)(hh + 3) * KLEN);
        const float* E0 = (const float*)&e0;
        const float* E1 = (const float*)&e1;
        const float* E2 = (const float*)&e2;
        const float* E3 = (const float*)&e3;
        const float w0 = wv_s[hbase + hh + 0], w1 = wv_s[hbase + hh + 1];
        const float w2 = wv_s[hbase + hh + 2], w3 = wv_s[hbase + hh + 3];
        #pragma unroll
        for (int i = 0; i < 4; ++i) {
            const float a0 = eq_s[i][hbase + hh + 0], a1 = eq_s[i][hbase + hh + 1];
            const float a2 = eq_s[i][hbase + hh + 2], a3 = eq_s[i][hbase + hh + 3];
            #pragma unroll
            for (int j = 0; j < 4; ++j) {
                float d0 = fmaf(a0, E0[j], 1.f);
                float d1 = fmaf(a1, E1[j], 1.f);
                float d2 = fmaf(a2, E2[j], 1.f);
                float d3 = fmaf(a3, E3[j], 1.f);
                float d01 = d0 * d1, d23 = d2 * d3;
                float n01 = fmaf(w1, d0, w0 * d1);
                float n23 = fmaf(w3, d2, w2 * d3);
                float top = fmaf(n23, d01, n01 * d23);
                acc[i][j] = fmaf(top, frcp(d01 * d23), acc[i][j]);
            }
        }
    }
    #pragma unroll
    for (int i = 0; i < 4; ++i) {
        float4 st; st.x = acc[i][0]; st.y = acc[i][1]; st.z = acc[i][2]; st.w = acc[i][3];
        *(float4*)&ps[hs][i][k4] = st;
    }
    __syncthreads();

    {
        const int q = t >> 7, kk = (t & 127) * 4;
        float4 s0 = *(const float4*)&ps[0][q][kk];
        float4 s1 = *(const float4*)&ps[1][q][kk];
        float4 s2 = *(const float4*)&ps[2][q][kk];
        float4 s3 = *(const float4*)&ps[3][q][kk];
        float4 r;
        r.x = fmaf(-2.f, s0.x + s1.x + s2.x + s3.x, wv_sum);
        r.y = fmaf(-2.f, s0.y + s1.y + s2.y + s3.y, wv_sum);
        r.z = fmaf(-2.f, s0.z + s1.z + s2.z + s3.z, wv_sum);
        r.w = fmaf(-2.f, s0.w + s1.w + s2.w + s3.w, wv_sum);
        *(float4*)&sc[q][kk] = r;
    }
    __syncthreads();

    if (wid < 4) {
        const int len = vlen[b];
        float s[8];
        float m = -3.0e38f;
        #pragma unroll
        for (int j = 0; j < 8; ++j) {
            int k = lane + j * 64;
            float v = sc[wid][k];
            v = (k < len) ? v : -1.0e6f;
            s[j] = v;
            m = fmaxf(m, v);
        }
        #pragma unroll
        for (int off = 32; off > 0; off >>= 1) m = fmaxf(m, __shfl_xor(m, off, 64));
        float sum = 0.f;
        #pragma unroll
        for (int j = 0; j < 8; ++j) {
            float ev = fexp2(1.4426950408889634f * (s[j] - m));
            s[j] = ev;
            sum += ev;
        }
        #pragma unroll
        for (int off = 32; off > 0; off >>= 1) sum += __shfl_xor(sum, off, 64);
        const float rs = frcp(sum);
        #pragma unroll
        for (int j = 0; j < 8; ++j) sc[wid][lane + j * 64] = s[j] * rs;
    }
    __syncthreads();

    float (*po)[4][VD] = (float (*)[4][VD])ps;
    const int c4 = lane * 4;
    const float* vb = values + (size_t)b * KLEN * VD + (size_t)(wid * 64) * VD + c4;
    float o[4][4] = {};
    for (int kk = 0; kk < 64; kk += 4) {
        const int k = wid * 64 + kk;
        float4 pr[4];
        pr[0] = *(const float4*)&sc[0][k];
        pr[1] = *(const float4*)&sc[1][k];
        pr[2] = *(const float4*)&sc[2][k];
        pr[3] = *(const float4*)&sc[3][k];
        #pragma unroll
        for (int j = 0; j < 4; ++j) {
            float4 v4 = *(const float4*)(vb + (size_t)(kk + j) * VD);
            #pragma unroll
            for (int r = 0; r < 4; ++r) {
                float pj = ((const float*)&pr[r])[j];
                o[r][0] = fmaf(pj, v4.x, o[r][0]);
                o[r][1] = fmaf(pj, v4.y, o[r][1]);
                o[r][2] = fmaf(pj, v4.z, o[r][2]);
                o[r][3] = fmaf(pj, v4.w, o[r][3]);
            }
        }
    }
    #pragma unroll
    for (int r = 0; r < 4; ++r) {
        float4 st; st.x = o[r][0]; st.y = o[r][1]; st.z = o[r][2]; st.w = o[r][3];
        *(float4*)&po[wid][r][c4] = st;
    }
    __syncthreads();

    #pragma unroll
    for (int u = 0; u < 2; ++u) {
        int idx = t + u * 512;
        int r = idx >> 8, c = idx & 255;
        float s = 0.f;
        #pragma unroll
        for (int sl = 0; sl < 8; ++sl) s += po[sl][r][c];
        out[(b * QLEN + q0 + r) * VD + c] = s;
    }
}

extern "C" void kernel_launch(void* const* d_in, const int* in_sizes, int n_in,
                              void* d_out, int out_size, void* d_ws, size_t ws_size,
                              hipStream_t stream) {
    const float* queries = (const float*)d_in[0];
    const float* keys    = (const float*)d_in[1];
    const float* values  = (const float*)d_in[2];
    const float* Wq      = (const float*)d_in[3];
    const float* Wk      = (const float*)d_in[4];
    const float* Wv      = (const float*)d_in[5];
    const int*   vl      = (const int*)d_in[6];
    float* out = (float*)d_out;

    float* Eq  = (float*)d_ws;                 // [2048][256]        (2 MB)
    float* Ekt = Eq + 2048 * 256;              // [16][256][512]     (8 MB)

    if (ws_size >= 11010048) {
        __bf16* Whi = (__bf16*)(Ekt + 16 * HD * KLEN);   // 131072 bf16
        __bf16* Wlo = Whi + 131072;                      // 131072 bf16
        conv_w<<<dim3(128), 256, 0, stream>>>(Wq, Wk, Whi, Wlo);
        mfma_proj<<<dim3(2, 160), 256, 0, stream>>>(queries, keys, Whi, Wlo, Eq, Ekt);
    } else {
        proj_exp_gemm<<<dim3(4, 160), 256, 0, stream>>>(queries, keys, Wq, Wk, Eq, Ekt);
    }
    fused_attn<<<dim3(512), 512, 0, stream>>>(Eq, Ekt, values, Wv, vl, out);
}

// Round 5
// 121.039 us; speedup vs baseline: 1.6526x; 1.0237x over previous
//
#include <hip/hip_runtime.h>

#define BQ   16
#define QLEN 128
#define KLEN 512
#define HD   256
#define VD   256

typedef __bf16 bf16x8 __attribute__((ext_vector_type(8)));
typedef __bf16 bf16x4 __attribute__((ext_vector_type(4)));
typedef float  f32x4  __attribute__((ext_vector_type(4)));

static __device__ __forceinline__ float fexp2(float x) {
#if __has_builtin(__builtin_amdgcn_exp2f)
    return __builtin_amdgcn_exp2f(x);
#else
    return exp2f(x);
#endif
}
static __device__ __forceinline__ float frcp(float x) {
#if __has_builtin(__builtin_amdgcn_rcpf)
    return __builtin_amdgcn_rcpf(x);
#else
    return 1.0f / x;
#endif
}

#define EXP_SCALE 2.8853900817779268f   // 2*log2(e)

// ---------------- MFMA projection GEMM (split-bf16, ~fp32 accurate) ----
// C[r][h] = sum_d A[r][d]*W[h][d];  E = exp2(EXP_SCALE * C).
// grid (2, 160): by<32 -> queries -> Eq row-major; else keys -> Ekt
// transposed [b][h][k]. Key blocks whose 64-row slab is entirely masked
// (local k >= valid_len) exit immediately -> Ekt stays poisoned there,
// which is harmless (softmax masks those k exactly to 0).
// W is split to bf16 hi/lo INLINE during staging (no separate conv pass).
// Tile 64x128, BK=32, 4 waves. a*w ~= hi*Whi + hi*Wlo + lo*Whi.
__global__ __launch_bounds__(256) void mfma_proj(
    const float* __restrict__ queries, const float* __restrict__ keys,
    const float* __restrict__ Wq, const float* __restrict__ Wk,
    const int* __restrict__ vlen,
    float* __restrict__ Eq, float* __restrict__ Ekt)
{
    __shared__ __bf16 Ahi_s[64][40];    // stride 40 bf16 = 80 B: 2-way max
    __shared__ __bf16 Alo_s[64][40];
    __shared__ __bf16 Whi_s[128][40];
    __shared__ __bf16 Wlo_s[128][40];

    const int t    = threadIdx.x;
    const int ln   = t & 63;
    const int w    = t >> 6;
    const int p    = ln & 15;
    const int quad = ln >> 4;
    const int bx = blockIdx.x, by = blockIdx.y;
    const bool isq = by < 32;
    const int row0 = by * 64;
    const int col0 = bx * 128;

    if (!isq) {   // block-uniform masked-key skip
        const int kr0 = row0 - 2048;
        if ((kr0 & 511) >= vlen[kr0 >> 9]) return;
    }

    const float* Ag = isq ? (queries + (size_t)row0 * HD)
                          : (keys + (size_t)(row0 - 2048) * HD);
    const float* Wg = isq ? Wq : Wk;

    const int ar = t >> 2, ac = (t & 3) * 8;     // A stage: 8 floats/thread
    const int wr = t >> 1, wc = (t & 1) * 16;    // W stage: 16 floats/thread

    float4 pa0, pa1, pw0, pw1, pw2, pw3;
    {
        const float* ap = Ag + ar * HD + ac;
        pa0 = *(const float4*)ap;
        pa1 = *(const float4*)(ap + 4);
        const float* wp = Wg + (size_t)(col0 + wr) * HD + wc;
        pw0 = *(const float4*)wp;       pw1 = *(const float4*)(wp + 4);
        pw2 = *(const float4*)(wp + 8); pw3 = *(const float4*)(wp + 12);
    }

    f32x4 acc[4][2] = {};

    for (int s = 0; s < 8; ++s) {
        __syncthreads();
        {
            float fa[8] = {pa0.x, pa0.y, pa0.z, pa0.w, pa1.x, pa1.y, pa1.z, pa1.w};
            bf16x8 h, l;
            #pragma unroll
            for (int j = 0; j < 8; ++j) {
                __bf16 hv = (__bf16)fa[j];
                h[j] = hv;
                l[j] = (__bf16)(fa[j] - (float)hv);
            }
            *(bf16x8*)&Ahi_s[ar][ac] = h;
            *(bf16x8*)&Alo_s[ar][ac] = l;

            float fw[16] = {pw0.x, pw0.y, pw0.z, pw0.w, pw1.x, pw1.y, pw1.z, pw1.w,
                            pw2.x, pw2.y, pw2.z, pw2.w, pw3.x, pw3.y, pw3.z, pw3.w};
            bf16x8 wh0, wh1, wl0, wl1;
            #pragma unroll
            for (int j = 0; j < 8; ++j) {
                __bf16 hv = (__bf16)fw[j];
                wh0[j] = hv;
                wl0[j] = (__bf16)(fw[j] - (float)hv);
                __bf16 hv1 = (__bf16)fw[8 + j];
                wh1[j] = hv1;
                wl1[j] = (__bf16)(fw[8 + j] - (float)hv1);
            }
            *(bf16x8*)&Whi_s[wr][wc]     = wh0;
            *(bf16x8*)&Whi_s[wr][wc + 8] = wh1;
            *(bf16x8*)&Wlo_s[wr][wc]     = wl0;
            *(bf16x8*)&Wlo_s[wr][wc + 8] = wl1;
        }
        __syncthreads();
        if (s < 7) {   // prefetch next K-slab
            const int kc = (s + 1) * 32;
            const float* ap = Ag + ar * HD + kc + ac;
            pa0 = *(const float4*)ap;
            pa1 = *(const float4*)(ap + 4);
            const float* wp = Wg + (size_t)(col0 + wr) * HD + kc + wc;
            pw0 = *(const float4*)wp;       pw1 = *(const float4*)(wp + 4);
            pw2 = *(const float4*)(wp + 8); pw3 = *(const float4*)(wp + 12);
        }
        bf16x8 ah[4], al[4], bh[2], bl[2];
        #pragma unroll
        for (int mi = 0; mi < 4; ++mi) {
            ah[mi] = *(const bf16x8*)&Ahi_s[mi * 16 + p][quad * 8];
            al[mi] = *(const bf16x8*)&Alo_s[mi * 16 + p][quad * 8];
        }
        #pragma unroll
        for (int ci = 0; ci < 2; ++ci) {
            const int hrow = w * 32 + ci * 16 + p;
            bh[ci] = *(const bf16x8*)&Whi_s[hrow][quad * 8];
            bl[ci] = *(const bf16x8*)&Wlo_s[hrow][quad * 8];
        }
        #pragma unroll
        for (int mi = 0; mi < 4; ++mi)
            #pragma unroll
            for (int ci = 0; ci < 2; ++ci) {
                acc[mi][ci] = __builtin_amdgcn_mfma_f32_16x16x32_bf16(ah[mi], bh[ci], acc[mi][ci], 0, 0, 0);
                acc[mi][ci] = __builtin_amdgcn_mfma_f32_16x16x32_bf16(ah[mi], bl[ci], acc[mi][ci], 0, 0, 0);
                acc[mi][ci] = __builtin_amdgcn_mfma_f32_16x16x32_bf16(al[mi], bh[ci], acc[mi][ci], 0, 0, 0);
            }
    }

    // epilogue: C/D layout col=lane&15, row=quad*4+reg
    #pragma unroll
    for (int mi = 0; mi < 4; ++mi)
        #pragma unroll
        for (int ci = 0; ci < 2; ++ci) {
            const int H  = col0 + w * 32 + ci * 16 + p;
            const int rl = mi * 16 + quad * 4;
            float e0 = fexp2(acc[mi][ci][0] * EXP_SCALE);
            float e1 = fexp2(acc[mi][ci][1] * EXP_SCALE);
            float e2 = fexp2(acc[mi][ci][2] * EXP_SCALE);
            float e3 = fexp2(acc[mi][ci][3] * EXP_SCALE);
            if (isq) {
                float* dst = Eq + (size_t)(row0 + rl) * HD + H;
                dst[0] = e0; dst[HD] = e1; dst[2 * HD] = e2; dst[3 * HD] = e3;
            } else {
                const int kr = row0 - 2048 + rl;
                const int b = kr >> 9, k0 = kr & 511;
                float4 st; st.x = e0; st.y = e1; st.z = e2; st.w = e3;
                *(float4*)(Ekt + ((size_t)b * HD + H) * KLEN + k0) = st;
            }
        }
}

// ---------------- fallback fp32 projection (if ws too small) ----------
__global__ __launch_bounds__(256) void proj_exp_gemm(
    const float* __restrict__ Qin, const float* __restrict__ Kin,
    const float* __restrict__ Wq, const float* __restrict__ Wk,
    float* __restrict__ Eq, float* __restrict__ Ekt)
{
    __shared__ union {
        struct { float a[2][16][68]; float w[2][16][68]; } s;
        float tb[64][65];
    } sh;

    const int t  = threadIdx.x;
    const int tx = t & 15, ty = t >> 4;
    const int bx = blockIdx.x, by = blockIdx.y;
    const bool isq = by < 32;
    const int row0 = isq ? by * 64 : (by - 32) * 64;
    const float* A = isq ? Qin : Kin;
    const float* W = isq ? Wq : Wk;
    const int lrow = t >> 2, ld0 = (t & 3) * 4;
    const float* Ab = A + (row0 + lrow) * HD;
    const float* Wb = W + (bx * 64 + lrow) * HD;

    float4 av = *(const float4*)(Ab + ld0);
    float4 wv = *(const float4*)(Wb + ld0);
    sh.s.a[0][ld0 + 0][lrow] = av.x; sh.s.a[0][ld0 + 1][lrow] = av.y;
    sh.s.a[0][ld0 + 2][lrow] = av.z; sh.s.a[0][ld0 + 3][lrow] = av.w;
    sh.s.w[0][ld0 + 0][lrow] = wv.x; sh.s.w[0][ld0 + 1][lrow] = wv.y;
    sh.s.w[0][ld0 + 2][lrow] = wv.z; sh.s.w[0][ld0 + 3][lrow] = wv.w;

    float acc[4][4] = {};
    int p = 0;
    for (int kc = 0; kc < HD; kc += 16) {
        if (kc + 16 < HD) {
            av = *(const float4*)(Ab + kc + 16 + ld0);
            wv = *(const float4*)(Wb + kc + 16 + ld0);
        }
        __syncthreads();
        if (kc + 16 < HD) {
            const int np = p ^ 1;
            sh.s.a[np][ld0 + 0][lrow] = av.x; sh.s.a[np][ld0 + 1][lrow] = av.y;
            sh.s.a[np][ld0 + 2][lrow] = av.z; sh.s.a[np][ld0 + 3][lrow] = av.w;
            sh.s.w[np][ld0 + 0][lrow] = wv.x; sh.s.w[np][ld0 + 1][lrow] = wv.y;
            sh.s.w[np][ld0 + 2][lrow] = wv.z; sh.s.w[np][ld0 + 3][lrow] = wv.w;
        }
        #pragma unroll
        for (int dd = 0; dd < 16; ++dd) {
            float4 a4 = *(const float4*)&sh.s.a[p][dd][ty * 4];
            float4 w4 = *(const float4*)&sh.s.w[p][dd][tx * 4];
            const float* af = (const float*)&a4;
            const float* wf = (const float*)&w4;
            #pragma unroll
            for (int i = 0; i < 4; ++i)
                #pragma unroll
                for (int j = 0; j < 4; ++j)
                    acc[i][j] = fmaf(af[i], wf[j], acc[i][j]);
        }
        p ^= 1;
    }

    float e[4][4];
    #pragma unroll
    for (int i = 0; i < 4; ++i)
        #pragma unroll
        for (int j = 0; j < 4; ++j)
            e[i][j] = fexp2(acc[i][j] * EXP_SCALE);

    if (isq) {
        float* Cb = Eq + (row0 + ty * 4) * HD + bx * 64 + tx * 4;
        #pragma unroll
        for (int i = 0; i < 4; ++i) {
            float4 st; st.x = e[i][0]; st.y = e[i][1]; st.z = e[i][2]; st.w = e[i][3];
            *(float4*)(Cb + i * HD) = st;
        }
    } else {
        __syncthreads();
        #pragma unroll
        for (int j = 0; j < 4; ++j) {
            float4 st; st.x = e[0][j]; st.y = e[1][j]; st.z = e[2][j]; st.w = e[3][j];
            *(float4*)&sh.tb[tx * 4 + j][ty * 4] = st;
        }
        __syncthreads();
        const int r = t >> 2, c0 = (t & 3) * 16;
        const int b = row0 >> 9, kbase = row0 & 511;
        float* dst = Ekt + ((size_t)b * HD + bx * 64 + r) * KLEN + kbase + c0;
        #pragma unroll
        for (int u = 0; u < 4; ++u) {
            float4 v = *(const float4*)&sh.tb[r][c0 + u * 4];
            *(float4*)(dst + u * 4) = v;
        }
    }
}

// ---------------- fused scores + masked softmax + PV ------------------
// grid 512: blk = qtile*16 + b  => XCD (blk%8) serves batches {x, x+8}
// whose Ekt+values+Eq slabs (~2.3 MB) fit that XCD's 4 MB L2.
// Wave-uniform skipping of fully-masked k-ranges (softmax exactly zeroes
// masked weights, so garbage partials there are harmless).
__global__ __launch_bounds__(512, 4) void fused_attn(
    const float* __restrict__ Eq, const float* __restrict__ Ekt,
    const float* __restrict__ values, const float* __restrict__ Wv,
    const int* __restrict__ vlen, float* __restrict__ out)
{
    __shared__ float eq_s[4][HD];
    __shared__ float wv_s[HD];
    __shared__ float sc[4][KLEN];
    __shared__ float ps[4][4][KLEN];   // phase-1 partials; aliased as po[8][4][VD]
    __shared__ float wred[4];

    const int t    = threadIdx.x;
    const int b    = blockIdx.x & 15;
    const int q0   = (blockIdx.x >> 4) * 4;
    const int lane = t & 63;
    const int wid  = t >> 6;
    const int len  = vlen[b];

    {
        const int h = t & 255, rr = t >> 8;
        eq_s[rr][h]     = Eq[(b * QLEN + q0 + rr) * HD + h];
        eq_s[rr + 2][h] = Eq[(b * QLEN + q0 + rr + 2) * HD + h];
        if (t < HD) {
            float w = Wv[t];
            wv_s[t] = w;
            float ws = w;
            #pragma unroll
            for (int off = 32; off > 0; off >>= 1) ws += __shfl_xor(ws, off, 64);
            if (lane == 0) wred[wid] = ws;
        }
    }
    __syncthreads();
    const float wv_sum = wred[0] + wred[1] + wred[2] + wred[3];

    // ---- Phase 1: scores. Wave = (h-slice, k-half); skip masked k-half.
    const int hs    = wid & 3, khalf = wid >> 2;
    if (khalf * 256 < len) {
        const int hbase = hs * 64;
        const int k4    = khalf * 256 + lane * 4;
        const float* ek = Ekt + ((size_t)b * HD + hbase) * KLEN + k4;
        float acc[4][4] = {};
        for (int hh = 0; hh < 64; hh += 4) {
            float4 e0 = *(const float4*)(ek + (size_t)(hh + 0) * KLEN);
            float4 e1 = *(const float4*)(ek + (size_t)(hh + 1) * KLEN);
            float4 e2 = *(const float4*)(ek + (size_t)(hh + 2) * KLEN);
            float4 e3 = *(const float4*)(ek + (size_t)(hh + 3) * KLEN);
            const float* E0 = (const float*)&e0;
            const float* E1 = (const float*)&e1;
            const float* E2 = (const float*)&e2;
            const float* E3 = (const float*)&e3;
            const float w0 = wv_s[hbase + hh + 0], w1 = wv_s[hbase + hh + 1];
            const float w2 = wv_s[hbase + hh + 2], w3 = wv_s[hbase + hh + 3];
            #pragma unroll
            for (int i = 0; i < 4; ++i) {
                const float a0 = eq_s[i][hbase + hh + 0], a1 = eq_s[i][hbase + hh + 1];
                const float a2 = eq_s[i][hbase + hh + 2], a3 = eq_s[i][hbase + hh + 3];
                #pragma unroll
                for (int j = 0; j < 4; ++j) {
                    float d0 = fmaf(a0, E0[j], 1.f);
                    float d1 = fmaf(a1, E1[j], 1.f);
                    float d2 = fmaf(a2, E2[j], 1.f);
                    float d3 = fmaf(a3, E3[j], 1.f);
                    float d01 = d0 * d1, d23 = d2 * d3;
                    float n01 = fmaf(w1, d0, w0 * d1);
                    float n23 = fmaf(w3, d2, w2 * d3);
                    float top = fmaf(n23, d01, n01 * d23);
                    acc[i][j] = fmaf(top, frcp(d01 * d23), acc[i][j]);
                }
            }
        }
        #pragma unroll
        for (int i = 0; i < 4; ++i) {
            float4 st; st.x = acc[i][0]; st.y = acc[i][1]; st.z = acc[i][2]; st.w = acc[i][3];
            *(float4*)&ps[hs][i][k4] = st;
        }
    }
    __syncthreads();

    {   // reduce 4 h-slices (garbage for masked k: masked to 0 below)
        const int q = t >> 7, kk = (t & 127) * 4;
        float4 s0 = *(const float4*)&ps[0][q][kk];
        float4 s1 = *(const float4*)&ps[1][q][kk];
        float4 s2 = *(const float4*)&ps[2][q][kk];
        float4 s3 = *(const float4*)&ps[3][q][kk];
        float4 r;
        r.x = fmaf(-2.f, s0.x + s1.x + s2.x + s3.x, wv_sum);
        r.y = fmaf(-2.f, s0.y + s1.y + s2.y + s3.y, wv_sum);
        r.z = fmaf(-2.f, s0.z + s1.z + s2.z + s3.z, wv_sum);
        r.w = fmaf(-2.f, s0.w + s1.w + s2.w + s3.w, wv_sum);
        *(float4*)&sc[q][kk] = r;
    }
    __syncthreads();

    // ---- Phase 2: masked softmax, wave w (w<4) handles row w.
    if (wid < 4) {
        float s[8];
        float m = -3.0e38f;
        #pragma unroll
        for (int j = 0; j < 8; ++j) {
            int k = lane + j * 64;
            float v = sc[wid][k];
            v = (k < len) ? v : -1.0e6f;
            s[j] = v;
            m = fmaxf(m, v);
        }
        #pragma unroll
        for (int off = 32; off > 0; off >>= 1) m = fmaxf(m, __shfl_xor(m, off, 64));
        float sum = 0.f;
        #pragma unroll
        for (int j = 0; j < 8; ++j) {
            float ev = fexp2(1.4426950408889634f * (s[j] - m));
            s[j] = ev;
            sum += ev;
        }
        #pragma unroll
        for (int off = 32; off > 0; off >>= 1) sum += __shfl_xor(sum, off, 64);
        const float rs = frcp(sum);
        #pragma unroll
        for (int j = 0; j < 8; ++j) sc[wid][lane + j * 64] = s[j] * rs;
    }
    __syncthreads();

    // ---- Phase 3: PV, k-sliced; skip fully-masked slices (zero partials).
    float (*po)[4][VD] = (float (*)[4][VD])ps;
    const int c4 = lane * 4;
    if (wid * 64 < len) {
        const float* vb = values + (size_t)b * KLEN * VD + (size_t)(wid * 64) * VD + c4;
        float o[4][4] = {};
        for (int kk = 0; kk < 64; kk += 4) {
            const int k = wid * 64 + kk;
            float4 pr[4];
            pr[0] = *(const float4*)&sc[0][k];
            pr[1] = *(const float4*)&sc[1][k];
            pr[2] = *(const float4*)&sc[2][k];
            pr[3] = *(const float4*)&sc[3][k];
            #pragma unroll
            for (int j = 0; j < 4; ++j) {
                float4 v4 = *(const float4*)(vb + (size_t)(kk + j) * VD);
                #pragma unroll
                for (int r = 0; r < 4; ++r) {
                    float pj = ((const float*)&pr[r])[j];
                    o[r][0] = fmaf(pj, v4.x, o[r][0]);
                    o[r][1] = fmaf(pj, v4.y, o[r][1]);
                    o[r][2] = fmaf(pj, v4.z, o[r][2]);
                    o[r][3] = fmaf(pj, v4.w, o[r][3]);
                }
            }
        }
        #pragma unroll
        for (int r = 0; r < 4; ++r) {
            float4 st; st.x = o[r][0]; st.y = o[r][1]; st.z = o[r][2]; st.w = o[r][3];
            *(float4*)&po[wid][r][c4] = st;
        }
    } else {
        float4 z; z.x = z.y = z.z = z.w = 0.f;
        #pragma unroll
        for (int r = 0; r < 4; ++r) *(float4*)&po[wid][r][c4] = z;
    }
    __syncthreads();

    #pragma unroll
    for (int u = 0; u < 2; ++u) {
        int idx = t + u * 512;
        int r = idx >> 8, c = idx & 255;
        float s = 0.f;
        #pragma unroll
        for (int sl = 0; sl < 8; ++sl) s += po[sl][r][c];
        out[(b * QLEN + q0 + r) * VD + c] = s;
    }
}

extern "C" void kernel_launch(void* const* d_in, const int* in_sizes, int n_in,
                              void* d_out, int out_size, void* d_ws, size_t ws_size,
                              hipStream_t stream) {
    const float* queries = (const float*)d_in[0];
    const float* keys    = (const float*)d_in[1];
    const float* values  = (const float*)d_in[2];
    const float* Wq      = (const float*)d_in[3];
    const float* Wk      = (const float*)d_in[4];
    const float* Wv      = (const float*)d_in[5];
    const int*   vl      = (const int*)d_in[6];
    float* out = (float*)d_out;

    float* Eq  = (float*)d_ws;                 // [2048][256]        (2 MB)
    float* Ekt = Eq + 2048 * 256;              // [16][256][512]     (8 MB)

    if (ws_size >= 10485760) {
        mfma_proj<<<dim3(2, 160), 256, 0, stream>>>(queries, keys, Wq, Wk, vl, Eq, Ekt);
    } else {
        proj_exp_gemm<<<dim3(4, 160), 256, 0, stream>>>(queries, keys, Wq, Wk, Eq, Ekt);
    }
    fused_attn<<<dim3(512), 512, 0, stream>>>(Eq, Ekt, values, Wv, vl, out);
}